// Round 4
// baseline (1879.399 us; speedup 1.0000x reference)
//
#include <hip/hip_runtime.h>
#include <hip/hip_bf16.h>
#include <cstdint>
#include <cstddef>

// Problem constants
#define Bq 16
#define Sq 512
#define Dq 1024
#define Hq 16
#define Lq 4
#define FFq 4096
#define Mq (Bq * Sq)  // 8192

typedef unsigned short ushort_t;
typedef __attribute__((ext_vector_type(8))) short short8;
typedef __attribute__((ext_vector_type(8))) unsigned short ushortx8;
typedef __attribute__((ext_vector_type(4))) unsigned short ushortx4;
typedef __attribute__((ext_vector_type(4))) float floatx4;

__device__ __forceinline__ float bf2f(ushort_t u) {
  union { unsigned int i; float f; } x;
  x.i = ((unsigned int)u) << 16;
  return x.f;
}
__device__ __forceinline__ ushort_t f2bf(float f) {
  unsigned int u = __float_as_uint(f);
  u += 0x7fffu + ((u >> 16) & 1u);
  return (ushort_t)(u >> 16);
}

// async global->LDS, 16B per lane; LDS dest is wave-uniform base + lane*16
#define GLL16(gp, lp) __builtin_amdgcn_global_load_lds( \
    (__attribute__((address_space(1))) void*)(gp),      \
    (__attribute__((address_space(3))) void*)(lp), 16, 0, 0)

// ---------------------------------------------------------------------------
// dtype probe: pe[1] (= cos(0) = 1.0) and ln1_g[0] (= 1.0).
// ---------------------------------------------------------------------------
__global__ void probe_kernel(const ushort_t* __restrict__ pe,
                             const ushort_t* __restrict__ g1,
                             int* __restrict__ flags)
{
  if (threadIdx.x == 0 && blockIdx.x == 0) {
    flags[0] = (pe[1] == (ushort_t)0x3F80u) ? 1 : 0;
    flags[1] = (g1[0] == (ushort_t)0x3F80u) ? 1 : 0;
  }
}

// fused small-tensor canonicalize: 10 segments in one dispatch
struct CvtArgs {
  const void* src[10];
  ushort_t*   dst[10];
  int         n[10];
  int         fi[10];
  int         cum[11];
};
__global__ __launch_bounds__(256) void convert_all_kernel(
    CvtArgs a, const int* __restrict__ flags)
{
  const int bidx = blockIdx.x;
  int s = 0;
  while (s < 9 && bidx >= a.cum[s + 1]) ++s;
  const int i = (bidx - a.cum[s]) * 256 + threadIdx.x;
  if (i >= a.n[s]) return;
  if (flags[a.fi[s]]) a.dst[s][i] = ((const ushort_t*)a.src[s])[i];
  else                a.dst[s][i] = f2bf(((const float*)a.src[s])[i]);
}

// ---------------------------------------------------------------------------
// GEMM: C[M,N] = A[M,K] (bf16 rm) * BT[N,K] + bias[n]. 128x128 tile, BK=32,
// 4 waves. T1 XCD slab swizzle + T2 LDS 16B-granule XOR swizzle (linear LDS
// dest for global_load_lds, inverse-swizzled global SOURCE, swizzled READ)
// + T4 counted-vmcnt 4-buffer pipeline (prefetch depth 3, raw s_barrier,
// never vmcnt(0) in steady state).
// Swizzle: granule (row, c4) of a [128][32]bf16 tile lives at LDS granule
// row*4 + (c4 ^ ((row>>1)&3)). Read of col-slice (16 consecutive rows, fixed
// c4) then touches 8 distinct 16B slots 2-way => conflict-free (m136).
// ---------------------------------------------------------------------------
__global__ __launch_bounds__(256) void gemm_bt_kernel(
    const ushort_t* __restrict__ A, const ushort_t* __restrict__ BT,
    const ushort_t* __restrict__ bias, ushort_t* __restrict__ C,
    int N, int K, int relu)
{
  __shared__ __align__(16) ushort_t As[4][4096];  // 4 bufs x 8 KB
  __shared__ __align__(16) ushort_t Bs[4][4096];

  const int t = threadIdx.x;
  const int lane = t & 63;
  const int w = t >> 6;
  const int la = lane & 15;
  const int lb = lane >> 4;

  // ---- XCD slab swizzle (bijective; gy is always a multiple of 8 here) ----
  int bx = blockIdx.x, by = blockIdx.y;
  {
    const int gx = gridDim.x, gy = gridDim.y;
    if ((gy & 7) == 0) {
      const int orig = by * gx + bx;
      const int xcd = orig & 7;
      const int local = orig >> 3;
      const int rows = gy >> 3;
      by = xcd * rows + local % rows;
      bx = local / rows;
    }
  }
  const long m0 = (long)by * 128;
  const long n0 = (long)bx * 128;
  const int nk = K >> 5;

  // staging geometry: tile = 512 granules of 16B; thread t covers flat
  // granules f0 = w*128+lane and f1 = f0+64 (two GLL16 per tile per array).
  const int f0 = (w << 7) + lane;
  const int f1 = f0 + 64;
  const int rA0 = f0 >> 2, rA1 = f1 >> 2;
  const int kA0 = ((f0 & 3) ^ ((rA0 >> 1) & 3)) << 3;  // elems
  const int kA1 = ((f1 & 3) ^ ((rA1 >> 1) & 3)) << 3;
  const ushort_t* gA0 = A + (m0 + rA0) * K + kA0;
  const ushort_t* gA1 = A + (m0 + rA1) * K + kA1;
  const ushort_t* gB0 = BT + (n0 + rA0) * K + kA0;
  const ushort_t* gB1 = BT + (n0 + rA1) * K + kA1;
  const int lo0 = (w * 2 + 0) * 512;  // wave-uniform LDS elem base
  const int lo1 = (w * 2 + 1) * 512;

  const floatx4 z4 = {0.f, 0.f, 0.f, 0.f};
  floatx4 acc[4][4];
#pragma unroll
  for (int i = 0; i < 4; ++i)
#pragma unroll
    for (int j = 0; j < 4; ++j) acc[i][j] = z4;

#define STAGE(buf, kt) do {                      \
    const long ko_ = (long)(kt) << 5;            \
    GLL16(gA0 + ko_, &As[(buf)][lo0]);           \
    GLL16(gA1 + ko_, &As[(buf)][lo1]);           \
    GLL16(gB0 + ko_, &Bs[(buf)][lo0]);           \
    GLL16(gB1 + ko_, &Bs[(buf)][lo1]);           \
  } while (0)

  STAGE(0, 0);
  STAGE(1, 1);
  STAGE(2, 2);

  const int wm = (w >> 1) * 64;
  const int wn = (w & 1) * 64;

  for (int kt = 0; kt < nk; ++kt) {
    const int rem = nk - 1 - kt;  // staged tiles beyond current
    if (rem >= 2)      asm volatile("s_waitcnt vmcnt(8)" ::: "memory");
    else if (rem == 1) asm volatile("s_waitcnt vmcnt(4)" ::: "memory");
    else               asm volatile("s_waitcnt vmcnt(0)" ::: "memory");
    __builtin_amdgcn_s_barrier();

    const int cur = kt & 3;
    short8 af[4], bfr[4];
#pragma unroll
    for (int mf = 0; mf < 4; ++mf) {
      const int r = wm + mf * 16 + la;
      af[mf] = *(const short8*)&As[cur][r * 32 + ((lb ^ ((r >> 1) & 3)) << 3)];
    }
#pragma unroll
    for (int nf = 0; nf < 4; ++nf) {
      const int r = wn + nf * 16 + la;
      bfr[nf] = *(const short8*)&Bs[cur][r * 32 + ((lb ^ ((r >> 1) & 3)) << 3)];
    }
#pragma unroll
    for (int mf = 0; mf < 4; ++mf)
#pragma unroll
      for (int nf = 0; nf < 4; ++nf)
        acc[mf][nf] = __builtin_amdgcn_mfma_f32_16x16x32_bf16(af[mf], bfr[nf], acc[mf][nf], 0, 0, 0);

    asm volatile("s_waitcnt lgkmcnt(0)" ::: "memory");
    __builtin_amdgcn_s_barrier();
    if (kt + 3 < nk) STAGE((kt + 3) & 3, kt + 3);
  }
#undef STAGE

  // epilogue: C/D layout col=lane&15, row=(lane>>4)*4+reg
#pragma unroll
  for (int nf = 0; nf < 4; ++nf) {
    const long col = n0 + wn + nf * 16 + la;
    const float bsv = bf2f(bias[col]);
#pragma unroll
    for (int mf = 0; mf < 4; ++mf) {
      const long row = m0 + wm + mf * 16 + lb * 4;
      ushort_t* cp = C + row * N + col;
      const floatx4 v = acc[mf][nf];
#pragma unroll
      for (int r = 0; r < 4; ++r) {
        float x = v[r] + bsv;
        if (relu) x = fmaxf(x, 0.0f);
        cp[(long)r * N] = f2bf(x);
      }
    }
  }
}

// ---------------------------------------------------------------------------
// Fused causal attention. kq: [B,S,D] (k==q), vt: [B,H,64,S] (V^T per head),
// fr: bf16 [B*S]. scores = (q.k)*0.125*fr[i], mask j>=i, row 0 zeroed.
// ---------------------------------------------------------------------------
__global__ __launch_bounds__(256) void attn_kernel(
    const ushort_t* __restrict__ kq, const ushort_t* __restrict__ vt,
    const ushort_t* __restrict__ fr, ushort_t* __restrict__ ao)
{
  __shared__ __align__(16) ushort_t P[4][64 * 72];
  const int t = threadIdx.x;
  const int lane = t & 63;
  const int w4 = t >> 6;
  const int wq = blockIdx.y * 4 + w4;
  const int b = blockIdx.x >> 4;
  const int h = blockIdx.x & 15;
  const int la = lane & 15;
  const int lb = lane >> 4;
  const int i0 = wq * 64;
  const long kbase = ((long)b * Sq) * Dq + h * 64;
  const long vbase = ((long)(b * Hq + h)) * (64L * Sq);

  short8 qf[4][2];
#pragma unroll
  for (int mf = 0; mf < 4; ++mf)
#pragma unroll
    for (int tt = 0; tt < 2; ++tt)
      qf[mf][tt] = *(const short8*)&kq[kbase + (long)(i0 + mf * 16 + la) * Dq + tt * 32 + lb * 8];

  float frs[4][4];
#pragma unroll
  for (int mf = 0; mf < 4; ++mf)
#pragma unroll
    for (int r = 0; r < 4; ++r)
      frs[mf][r] = 0.125f * bf2f(fr[b * Sq + i0 + mf * 16 + lb * 4 + r]);

  const floatx4 z4 = {0.f, 0.f, 0.f, 0.f};
  floatx4 o[4][4];
  float mrun[4][4], lrun[4][4];
#pragma unroll
  for (int mf = 0; mf < 4; ++mf)
#pragma unroll
    for (int x = 0; x < 4; ++x) {
      o[mf][x] = z4;
      mrun[mf][x] = -1e30f;
      lrun[mf][x] = 0.0f;
    }

  for (int jt = 0; jt <= wq; ++jt) {
    const int j0 = jt * 64;
    floatx4 s[4][4];
#pragma unroll
    for (int mf = 0; mf < 4; ++mf)
#pragma unroll
      for (int jf = 0; jf < 4; ++jf) s[mf][jf] = z4;

#pragma unroll
    for (int tt = 0; tt < 2; ++tt) {
      short8 kf[4];
#pragma unroll
      for (int jf = 0; jf < 4; ++jf)
        kf[jf] = *(const short8*)&kq[kbase + (long)(j0 + jf * 16 + la) * Dq + tt * 32 + lb * 8];
#pragma unroll
      for (int mf = 0; mf < 4; ++mf)
#pragma unroll
        for (int jf = 0; jf < 4; ++jf)
          s[mf][jf] = __builtin_amdgcn_mfma_f32_16x16x32_bf16(qf[mf][tt], kf[jf], s[mf][jf], 0, 0, 0);
    }

    const bool diag = (jt == wq);
#pragma unroll
    for (int mf = 0; mf < 4; ++mf)
#pragma unroll
      for (int jf = 0; jf < 4; ++jf)
#pragma unroll
        for (int r = 0; r < 4; ++r) {
          float x = s[mf][jf][r] * frs[mf][r];
          if (diag && (j0 + jf * 16 + la) >= (i0 + mf * 16 + lb * 4 + r)) x = -1e30f;
          s[mf][jf][r] = x;
        }

#pragma unroll
    for (int mf = 0; mf < 4; ++mf)
#pragma unroll
      for (int r = 0; r < 4; ++r) {
        float pm = fmaxf(fmaxf(s[mf][0][r], s[mf][1][r]), fmaxf(s[mf][2][r], s[mf][3][r]));
        pm = fmaxf(pm, __shfl_xor(pm, 1));
        pm = fmaxf(pm, __shfl_xor(pm, 2));
        pm = fmaxf(pm, __shfl_xor(pm, 4));
        pm = fmaxf(pm, __shfl_xor(pm, 8));
        const float mo = mrun[mf][r];
        const float mn = fmaxf(mo, pm);
        const float sc = __expf(mo - mn);
        mrun[mf][r] = mn;
        float rs = 0.0f;
#pragma unroll
        for (int jf = 0; jf < 4; ++jf) {
          const float p = __expf(s[mf][jf][r] - mn);
          s[mf][jf][r] = p;
          rs += p;
        }
        rs += __shfl_xor(rs, 1);
        rs += __shfl_xor(rs, 2);
        rs += __shfl_xor(rs, 4);
        rs += __shfl_xor(rs, 8);
        lrun[mf][r] = lrun[mf][r] * sc + rs;
#pragma unroll
        for (int df = 0; df < 4; ++df) o[mf][df][r] *= sc;
      }

    // P tile is wave-private LDS; same-wave ds_write->ds_read, no barrier
#pragma unroll
    for (int mf = 0; mf < 4; ++mf)
#pragma unroll
      for (int jf = 0; jf < 4; ++jf)
#pragma unroll
        for (int r = 0; r < 4; ++r)
          P[w4][(mf * 16 + lb * 4 + r) * 72 + jf * 16 + la] = f2bf(s[mf][jf][r]);

#pragma unroll
    for (int tt = 0; tt < 2; ++tt) {
      short8 pf[4], vf[4];
#pragma unroll
      for (int mf = 0; mf < 4; ++mf)
        pf[mf] = *(const short8*)&P[w4][(mf * 16 + la) * 72 + tt * 32 + lb * 8];
#pragma unroll
      for (int df = 0; df < 4; ++df)
        vf[df] = *(const short8*)&vt[vbase + (long)(df * 16 + la) * Sq + j0 + tt * 32 + lb * 8];
#pragma unroll
      for (int mf = 0; mf < 4; ++mf)
#pragma unroll
        for (int df = 0; df < 4; ++df)
          o[mf][df] = __builtin_amdgcn_mfma_f32_16x16x32_bf16(pf[mf], vf[df], o[mf][df], 0, 0, 0);
    }
  }

#pragma unroll
  for (int mf = 0; mf < 4; ++mf)
#pragma unroll
    for (int df = 0; df < 4; ++df)
#pragma unroll
      for (int r = 0; r < 4; ++r) {
        const int ii = i0 + mf * 16 + lb * 4 + r;
        const float vv = (ii == 0) ? 0.0f : o[mf][df][r] / lrun[mf][r];
        ao[((long)b * Sq + ii) * Dq + h * 64 + df * 16 + la] = f2bf(vv);
      }
}

// ---------------------------------------------------------------------------
// Fused residual-add + LayerNorm. final_==1: write d_out per flags[0] dtype.
// ---------------------------------------------------------------------------
__global__ __launch_bounds__(256) void ln_kernel(
    float* __restrict__ xf, const ushort_t* __restrict__ add,
    const ushort_t* __restrict__ g, const ushort_t* __restrict__ bb,
    ushort_t* __restrict__ outb, float* __restrict__ outf,
    const int* __restrict__ flags, int final_)
{
  __shared__ float red[2][4];
  const long row = blockIdx.x;
  const int t = threadIdx.x;
  const int c = t * 4;
  float* xr = xf + row * Dq;
  const ushort_t* ar = add + row * Dq;

  floatx4 xv = *(floatx4*)&xr[c];
  ushortx4 av = *(const ushortx4*)&ar[c];
  float v[4];
  float s1 = 0.f, s2 = 0.f;
#pragma unroll
  for (int e = 0; e < 4; ++e) {
    v[e] = xv[e] + bf2f(av[e]);
    s1 += v[e];
    s2 += v[e] * v[e];
  }
#pragma unroll
  for (int m = 1; m < 64; m <<= 1) {
    s1 += __shfl_xor(s1, m);
    s2 += __shfl_xor(s2, m);
  }
  const int lane = t & 63, w = t >> 6;
  if (lane == 0) { red[0][w] = s1; red[1][w] = s2; }
  __syncthreads();
  s1 = red[0][0] + red[0][1] + red[0][2] + red[0][3];
  s2 = red[1][0] + red[1][1] + red[1][2] + red[1][3];
  const float mean = s1 * (1.0f / Dq);
  const float var = fmaxf(s2 * (1.0f / Dq) - mean * mean, 0.0f);
  const float rstd = rsqrtf(var + 1e-5f);
  ushortx4 gv = *(const ushortx4*)&g[c];
  ushortx4 bv = *(const ushortx4*)&bb[c];
  ushortx4 ob;
  floatx4 xo;
#pragma unroll
  for (int e = 0; e < 4; ++e) {
    const float y = (v[e] - mean) * rstd * bf2f(gv[e]) + bf2f(bv[e]);
    xo[e] = y;
    ob[e] = f2bf(y);
  }
  *(floatx4*)&xr[c] = xo;
  if (final_ && !flags[0]) {
    *(floatx4*)&outf[row * Dq + c] = xo;
  } else {
    *(ushortx4*)&outb[row * Dq + c] = ob;
  }
}

// x = qe + pe (fp32 + bf16), y = qa + pe (bf16); flag-aware source dtype
__global__ __launch_bounds__(256) void addpe_kernel(
    const void* __restrict__ qe, const void* __restrict__ qa,
    const void* __restrict__ pe, float* __restrict__ xf,
    ushort_t* __restrict__ xb, ushort_t* __restrict__ yb,
    const int* __restrict__ flags)
{
  const long i = ((long)blockIdx.x * 256 + threadIdx.x) * 8;
  const long sd = i & ((long)Sq * Dq - 1);
  const bool isb = flags[0] != 0;
  float q[8], a[8], p[8];
  if (isb) {
    ushortx8 q8 = *(const ushortx8*)((const ushort_t*)qe + i);
    ushortx8 a8 = *(const ushortx8*)((const ushort_t*)qa + i);
    ushortx8 p8 = *(const ushortx8*)((const ushort_t*)pe + sd);
#pragma unroll
    for (int e = 0; e < 8; ++e) { q[e] = bf2f(q8[e]); a[e] = bf2f(a8[e]); p[e] = bf2f(p8[e]); }
  } else {
    const float* qp = (const float*)qe + i;
    const float* ap = (const float*)qa + i;
    const float* pp = (const float*)pe + sd;
    floatx4 q0 = *(const floatx4*)qp, q1 = *(const floatx4*)(qp + 4);
    floatx4 a0 = *(const floatx4*)ap, a1 = *(const floatx4*)(ap + 4);
    floatx4 p0 = *(const floatx4*)pp, p1 = *(const floatx4*)(pp + 4);
#pragma unroll
    for (int e = 0; e < 4; ++e) {
      q[e] = q0[e]; q[e + 4] = q1[e];
      a[e] = a0[e]; a[e + 4] = a1[e];
      p[e] = p0[e]; p[e + 4] = p1[e];
    }
  }
  ushortx8 xo, yo;
  floatx4 f0, f1;
#pragma unroll
  for (int e = 0; e < 8; ++e) {
    const float xvv = (isb ? q[e] : bf2f(f2bf(q[e]))) + (isb ? p[e] : bf2f(f2bf(p[e])));
    const float yvv = (isb ? a[e] : bf2f(f2bf(a[e]))) + (isb ? p[e] : bf2f(f2bf(p[e])));
    if (e < 4) { f0[e] = xvv; } else { f1[e - 4] = xvv; }
    xo[e] = f2bf(xvv);
    yo[e] = f2bf(yvv);
  }
  *(floatx4*)&xf[i] = f0;
  *(floatx4*)&xf[i + 4] = f1;
  *(ushortx8*)&xb[i] = xo;
  *(ushortx8*)&yb[i] = yo;
}

// dst[z][n][k] = src[z][k][n]; flag-aware source dtype (weights: flags[1])
__global__ __launch_bounds__(256) void transpose_kernel(
    const void* __restrict__ src, ushort_t* __restrict__ dst, int K, int N,
    const int* __restrict__ flags)
{
  __shared__ __align__(16) ushort_t tile[64][72];
  const bool isb = flags[1] != 0;
  const long base = (long)blockIdx.z * K * N;
  const int k0 = blockIdx.y * 64, n0 = blockIdx.x * 64;
  const int t = threadIdx.x;
  const int r = t >> 3;
  const int cc = (t & 7) << 3;
#pragma unroll
  for (int it = 0; it < 2; ++it) {
    const int rr = r + it * 32;
    const long gi = base + (long)(k0 + rr) * N + n0 + cc;
    if (isb) {
      *(short8*)&tile[rr][cc] = *(const short8*)((const ushort_t*)src + gi);
    } else {
      const float* sf = (const float*)src + gi;
      floatx4 v0 = *(const floatx4*)sf;
      floatx4 v1 = *(const floatx4*)(sf + 4);
#pragma unroll
      for (int e = 0; e < 4; ++e) {
        tile[rr][cc + e] = f2bf(v0[e]);
        tile[rr][cc + 4 + e] = f2bf(v1[e]);
      }
    }
  }
  __syncthreads();
#pragma unroll
  for (int it = 0; it < 2; ++it) {
    const int rr = r + it * 32;
    short8 v;
#pragma unroll
    for (int e = 0; e < 8; ++e) v[e] = (short)tile[cc + e][rr];
    *(short8*)&dst[base + (long)(n0 + rr) * K + k0 + cc] = v;
  }
}

// vt[b][h][d][j] = vb[b][j][h*64+d]  (vb is bf16 workspace, no flag needed)
__global__ __launch_bounds__(256) void vtrans_kernel(
    const ushort_t* __restrict__ vb, ushort_t* __restrict__ vt)
{
  __shared__ __align__(16) ushort_t tile[64][72];
  const int b = blockIdx.y >> 4, h = blockIdx.y & 15;
  const int j0 = blockIdx.x * 64;
  const int t = threadIdx.x;
  const int r = t >> 3;
  const int cc = (t & 7) << 3;
#pragma unroll
  for (int it = 0; it < 2; ++it) {
    const int rr = r + it * 32;
    *(short8*)&tile[rr][cc] = *(const short8*)&vb[((long)b * Sq + j0 + rr) * Dq + h * 64 + cc];
  }
  __syncthreads();
#pragma unroll
  for (int it = 0; it < 2; ++it) {
    const int rr = r + it * 32;
    short8 v;
#pragma unroll
    for (int e = 0; e < 8; ++e) v[e] = (short)tile[cc + e][rr];
    *(short8*)&vt[((long)(b * Hq + h) * 64 + rr) * Sq + j0 + cc] = v;
  }
}

extern "C" void kernel_launch(void* const* d_in, const int* in_sizes, int n_in,
                              void* d_out, int out_size, void* d_ws, size_t ws_size,
                              hipStream_t stream)
{
  if (n_in < 18) return;
  const void* qe  = d_in[0];
  const void* qa  = d_in[1];
  const void* fr  = d_in[2];
  const void* pe  = d_in[3];
  const void* Wk  = d_in[4];
  const void* bk  = d_in[5];
  const void* Wv  = d_in[6];
  const void* bv  = d_in[7];
  const void* Wo  = d_in[8];
  const void* bo  = d_in[9];
  const void* W1  = d_in[10];
  const void* b1  = d_in[11];
  const void* W2  = d_in[12];
  const void* b2  = d_in[13];
  const void* g1  = d_in[14];
  const void* be1 = d_in[15];
  const void* g2  = d_in[16];
  const void* be2 = d_in[17];

  char* ws = (char*)d_ws;
  const size_t SM = 243269632L;
  const size_t NEED = SM + 114752L;
  if (ws_size < NEED) return;

  float*    xf   = (float*)   (ws + 0L);
  ushort_t* xb   = (ushort_t*)(ws + 33554432L);
  ushort_t* yb   = (ushort_t*)(ws + 50331648L);
  ushort_t* tmpD = (ushort_t*)(ws + 67108864L);
  ushort_t* WkT  = (ushort_t*)(ws + 83886080L);
  ushort_t* WvT  = (ushort_t*)(ws + 92274688L);
  ushort_t* WoT  = (ushort_t*)(ws + 100663296L);
  ushort_t* W1T  = (ushort_t*)(ws + 109051904L);
  ushort_t* W2T  = (ushort_t*)(ws + 142606336L);
  ushort_t* kb   = (ushort_t*)(ws + 176160768L);
  ushort_t* vbf  = (ushort_t*)(ws + 192937984L);
  ushort_t* vtb  = (ushort_t*)(ws + 209715200L);
  ushort_t* ff1  = kb;  // 64 MiB region, disjoint lifetime

  int*      flags = (int*)(ws + SM);
  ushort_t* frc  = (ushort_t*)(ws + SM + 64);
  ushort_t* bkc  = (ushort_t*)(ws + SM + 16448);
  ushort_t* bvc  = (ushort_t*)(ws + SM + 24640);
  ushort_t* boc  = (ushort_t*)(ws + SM + 32832);
  ushort_t* b1c  = (ushort_t*)(ws + SM + 41024);
  ushort_t* b2c  = (ushort_t*)(ws + SM + 73792);
  ushort_t* g1c  = (ushort_t*)(ws + SM + 81984);
  ushort_t* be1c = (ushort_t*)(ws + SM + 90176);
  ushort_t* g2c  = (ushort_t*)(ws + SM + 98368);
  ushort_t* be2c = (ushort_t*)(ws + SM + 106560);

  probe_kernel<<<1, 64, 0, stream>>>((const ushort_t*)pe, (const ushort_t*)g1, flags);

  {
    CvtArgs a;
    const void* srcs[10] = {fr, bk, bv, bo, b1, b2, g1, be1, g2, be2};
    ushort_t*   dsts[10] = {frc, bkc, bvc, boc, b1c, b2c, g1c, be1c, g2c, be2c};
    const int   ns[10]   = {8192, 4096, 4096, 4096, 16384, 4096, 4096, 4096, 4096, 4096};
    int cum = 0;
    for (int s = 0; s < 10; ++s) {
      a.src[s] = srcs[s]; a.dst[s] = dsts[s]; a.n[s] = ns[s];
      a.fi[s] = (s == 0) ? 0 : 1;
      a.cum[s] = cum;
      cum += (ns[s] + 255) / 256;
    }
    a.cum[10] = cum;
    convert_all_kernel<<<cum, 256, 0, stream>>>(a, flags);
  }

  transpose_kernel<<<dim3(16, 16, 4), 256, 0, stream>>>(Wk, WkT, 1024, 1024, flags);
  transpose_kernel<<<dim3(16, 16, 4), 256, 0, stream>>>(Wv, WvT, 1024, 1024, flags);
  transpose_kernel<<<dim3(16, 16, 4), 256, 0, stream>>>(Wo, WoT, 1024, 1024, flags);
  transpose_kernel<<<dim3(64, 16, 4), 256, 0, stream>>>(W1, W1T, 1024, 4096, flags);
  transpose_kernel<<<dim3(16, 64, 4), 256, 0, stream>>>(W2, W2T, 4096, 1024, flags);

  addpe_kernel<<<4096, 256, 0, stream>>>(qe, qa, pe, xf, xb, yb, flags);

  for (int l = 0; l < 4; ++l) {
    gemm_bt_kernel<<<dim3(8, 64), 256, 0, stream>>>(xb, WkT + (long)l * 1048576, bkc + l * 1024, kb, 1024, 1024, 0);
    gemm_bt_kernel<<<dim3(8, 64), 256, 0, stream>>>(yb, WvT + (long)l * 1048576, bvc + l * 1024, vbf, 1024, 1024, 0);
    vtrans_kernel<<<dim3(8, 256), 256, 0, stream>>>(vbf, vtb);
    attn_kernel<<<dim3(256, 2), 256, 0, stream>>>(kb, vtb, frc, vbf);  // ao aliases vbf
    gemm_bt_kernel<<<dim3(8, 64), 256, 0, stream>>>(vbf, WoT + (long)l * 1048576, boc + l * 1024, tmpD, 1024, 1024, 0);
    ln_kernel<<<8192, 256, 0, stream>>>(xf, tmpD, g1c + l * 1024, be1c + l * 1024, xb, nullptr, flags, 0);
    gemm_bt_kernel<<<dim3(32, 64), 256, 0, stream>>>(xb, W1T + (long)l * 4194304, b1c + l * 4096, ff1, 4096, 1024, 1);
    gemm_bt_kernel<<<dim3(8, 64), 256, 0, stream>>>(ff1, W2T + (long)l * 4194304, b2c + l * 1024, tmpD, 1024, 4096, 0);
    if (l == 3) {
      ln_kernel<<<8192, 256, 0, stream>>>(xf, tmpD, g2c + l * 1024, be2c + l * 1024,
                                          (ushort_t*)d_out, (float*)d_out, flags, 1);
    } else {
      ln_kernel<<<8192, 256, 0, stream>>>(xf, tmpD, g2c + l * 1024, be2c + l * 1024,
                                          xb, nullptr, flags, 0);
    }
  }
}

// Round 5
// 1790.116 us; speedup vs baseline: 1.0499x; 1.0499x over previous
//
#include <hip/hip_runtime.h>
#include <hip/hip_bf16.h>
#include <cstdint>
#include <cstddef>

// Problem constants
#define Bq 16
#define Sq 512
#define Dq 1024
#define Hq 16
#define Lq 4
#define FFq 4096
#define Mq (Bq * Sq)  // 8192

typedef unsigned short ushort_t;
typedef __attribute__((ext_vector_type(8))) short short8;
typedef __attribute__((ext_vector_type(8))) unsigned short ushortx8;
typedef __attribute__((ext_vector_type(4))) unsigned short ushortx4;
typedef __attribute__((ext_vector_type(4))) float floatx4;

__device__ __forceinline__ float bf2f(ushort_t u) {
  union { unsigned int i; float f; } x;
  x.i = ((unsigned int)u) << 16;
  return x.f;
}
__device__ __forceinline__ ushort_t f2bf(float f) {
  unsigned int u = __float_as_uint(f);
  u += 0x7fffu + ((u >> 16) & 1u);
  return (ushort_t)(u >> 16);
}

// async global->LDS, 16B per lane; LDS dest is wave-uniform base + lane*16
#define GLL16(gp, lp) __builtin_amdgcn_global_load_lds( \
    (__attribute__((address_space(1))) void*)(gp),      \
    (__attribute__((address_space(3))) void*)(lp), 16, 0, 0)

// ---------------------------------------------------------------------------
// dtype probe: pe[1] (= cos(0) = 1.0) and ln1_g[0] (= 1.0).
// ---------------------------------------------------------------------------
__global__ void probe_kernel(const ushort_t* __restrict__ pe,
                             const ushort_t* __restrict__ g1,
                             int* __restrict__ flags)
{
  if (threadIdx.x == 0 && blockIdx.x == 0) {
    flags[0] = (pe[1] == (ushort_t)0x3F80u) ? 1 : 0;
    flags[1] = (g1[0] == (ushort_t)0x3F80u) ? 1 : 0;
  }
}

// fused small-tensor canonicalize: 10 segments in one dispatch
struct CvtArgs {
  const void* src[10];
  ushort_t*   dst[10];
  int         n[10];
  int         fi[10];
  int         cum[11];
};
__global__ __launch_bounds__(256) void convert_all_kernel(
    CvtArgs a, const int* __restrict__ flags)
{
  const int bidx = blockIdx.x;
  int s = 0;
  while (s < 9 && bidx >= a.cum[s + 1]) ++s;
  const int i = (bidx - a.cum[s]) * 256 + threadIdx.x;
  if (i >= a.n[s]) return;
  if (flags[a.fi[s]]) a.dst[s][i] = ((const ushort_t*)a.src[s])[i];
  else                a.dst[s][i] = f2bf(((const float*)a.src[s])[i]);
}

// ---------------------------------------------------------------------------
// GEMM: C[M,N] = A[M,K] (bf16 rm) * BT[N,K] + bias[n].
// HIGH-OCCUPANCY config: 128x64 tile, BK=32, 4 waves (each 64x32 = 4x2 frags
// of 16x16x32), LDS 24KB double-buffer -> 5-6 blocks/CU co-resident (the m102
// occupancy curve is the measured lever; sync flavor was not).
// Proven pieces kept verbatim: T1 XCD slab swizzle (r3: fetch -4x), T2
// source-side granule swizzle (r4: bank conflicts -> 0), m97 2-phase loop,
// frag/epilogue layout (passed r2-r4).
// blockIdx.z selects pointer set (batches K-proj and V-proj in one dispatch).
// ---------------------------------------------------------------------------
__global__ __launch_bounds__(256) void gemm_bt_kernel(
    const ushort_t* __restrict__ A0, const ushort_t* __restrict__ BT0,
    const ushort_t* __restrict__ bias0, ushort_t* __restrict__ C0,
    const ushort_t* __restrict__ A1, const ushort_t* __restrict__ BT1,
    const ushort_t* __restrict__ bias1, ushort_t* __restrict__ C1,
    int N, int K, int relu)
{
  __shared__ __align__(16) ushort_t As[2][128 * 32];  // 8KB per buf
  __shared__ __align__(16) ushort_t Bs[2][64 * 32];   // 4KB per buf

  const ushort_t* A    = blockIdx.z ? A1 : A0;
  const ushort_t* BT   = blockIdx.z ? BT1 : BT0;
  const ushort_t* bias = blockIdx.z ? bias1 : bias0;
  ushort_t*       C    = blockIdx.z ? C1 : C0;

  const int t = threadIdx.x;
  const int lane = t & 63;
  const int w = t >> 6;
  const int la = lane & 15;
  const int lb = lane >> 4;

  // ---- T1 XCD slab swizzle (bijective; gy = 64 here, multiple of 8) ----
  int bx = blockIdx.x, by = blockIdx.y;
  {
    const int gx = gridDim.x, gy = gridDim.y;
    if ((gy & 7) == 0) {
      const int orig = by * gx + bx;
      const int xcd = orig & 7;
      const int local = orig >> 3;
      const int rows = gy >> 3;
      by = xcd * rows + local % rows;
      bx = local / rows;
    }
  }
  const long m0 = (long)by * 128;
  const long n0 = (long)bx * 64;
  const int nk = K >> 5;

  // staging: A tile = 512 granules(16B), B tile = 256; thread t covers
  // A granules {t, t+256} and B granule {t}; granule f -> row f>>2, cg f&3;
  // T2 inverse swizzle on the SOURCE column: cgs = cg ^ ((row>>1)&3).
  const int rA0 = t >> 2;            // 0..63
  const int rA1 = 64 + (t >> 2);     // 64..127
  const int cg  = t & 3;
  const int cA0 = (cg ^ ((rA0 >> 1) & 3)) << 3;
  const int cA1 = (cg ^ ((rA1 >> 1) & 3)) << 3;
  const ushort_t* gA0 = A + (m0 + rA0) * K + cA0;
  const ushort_t* gA1 = A + (m0 + rA1) * K + cA1;
  const ushort_t* gB0 = BT + (n0 + rA0) * K + cA0;   // B rows 0..63 (same map)
  const int loA0 = (w * 64) * 8;          // wave-uniform LDS elem bases
  const int loA1 = (256 + w * 64) * 8;
  const int loB0 = (w * 64) * 8;

#define STAGE(buf, kt) do {                      \
    const long ko_ = (long)(kt) << 5;            \
    GLL16(gA0 + ko_, &As[(buf)][loA0]);          \
    GLL16(gA1 + ko_, &As[(buf)][loA1]);          \
    GLL16(gB0 + ko_, &Bs[(buf)][loB0]);          \
  } while (0)

  const floatx4 z4 = {0.f, 0.f, 0.f, 0.f};
  floatx4 acc[4][2];
#pragma unroll
  for (int i = 0; i < 4; ++i)
#pragma unroll
    for (int j = 0; j < 2; ++j) acc[i][j] = z4;

  STAGE(0, 0);
  __syncthreads();

  const int wm = (w >> 1) * 64;   // wave M-offset (wr*64)
  const int wn = (w & 1) * 32;    // wave N-offset (wc*32)
  int cur = 0;

  for (int kt = 0; kt < nk; ++kt) {
    if (kt + 1 < nk) STAGE(cur ^ 1, kt + 1);

    short8 af[4], bfr[2];
#pragma unroll
    for (int mf = 0; mf < 4; ++mf) {
      const int r = wm + mf * 16 + la;
      af[mf] = *(const short8*)&As[cur][r * 32 + ((lb ^ ((r >> 1) & 3)) << 3)];
    }
#pragma unroll
    for (int nf = 0; nf < 2; ++nf) {
      const int r = wn + nf * 16 + la;
      bfr[nf] = *(const short8*)&Bs[cur][r * 32 + ((lb ^ ((r >> 1) & 3)) << 3)];
    }
#pragma unroll
    for (int mf = 0; mf < 4; ++mf)
#pragma unroll
      for (int nf = 0; nf < 2; ++nf)
        acc[mf][nf] = __builtin_amdgcn_mfma_f32_16x16x32_bf16(af[mf], bfr[nf], acc[mf][nf], 0, 0, 0);

    __syncthreads();   // drains vmcnt/lgkm; hidden by 5-way block co-residency
    cur ^= 1;
  }
#undef STAGE

  // epilogue: C/D layout col=lane&15, row=(lane>>4)*4+reg
#pragma unroll
  for (int nf = 0; nf < 2; ++nf) {
    const long col = n0 + wn + nf * 16 + la;
    const float bsv = bf2f(bias[col]);
#pragma unroll
    for (int mf = 0; mf < 4; ++mf) {
      const long row = m0 + wm + mf * 16 + lb * 4;
      ushort_t* cp = C + row * N + col;
      const floatx4 v = acc[mf][nf];
#pragma unroll
      for (int r = 0; r < 4; ++r) {
        float x = v[r] + bsv;
        if (relu) x = fmaxf(x, 0.0f);
        cp[(long)r * N] = f2bf(x);
      }
    }
  }
}

// ---------------------------------------------------------------------------
// Fused causal attention. kq: [B,S,D] (k==q), vt: [B,H,64,S] (V^T per head),
// fr: bf16 [B*S]. scores = (q.k)*0.125*fr[i], mask j>=i, row 0 zeroed.
// ---------------------------------------------------------------------------
__global__ __launch_bounds__(256) void attn_kernel(
    const ushort_t* __restrict__ kq, const ushort_t* __restrict__ vt,
    const ushort_t* __restrict__ fr, ushort_t* __restrict__ ao)
{
  __shared__ __align__(16) ushort_t P[4][64 * 72];
  const int t = threadIdx.x;
  const int lane = t & 63;
  const int w4 = t >> 6;
  const int wq = blockIdx.y * 4 + w4;
  const int b = blockIdx.x >> 4;
  const int h = blockIdx.x & 15;
  const int la = lane & 15;
  const int lb = lane >> 4;
  const int i0 = wq * 64;
  const long kbase = ((long)b * Sq) * Dq + h * 64;
  const long vbase = ((long)(b * Hq + h)) * (64L * Sq);

  short8 qf[4][2];
#pragma unroll
  for (int mf = 0; mf < 4; ++mf)
#pragma unroll
    for (int tt = 0; tt < 2; ++tt)
      qf[mf][tt] = *(const short8*)&kq[kbase + (long)(i0 + mf * 16 + la) * Dq + tt * 32 + lb * 8];

  float frs[4][4];
#pragma unroll
  for (int mf = 0; mf < 4; ++mf)
#pragma unroll
    for (int r = 0; r < 4; ++r)
      frs[mf][r] = 0.125f * bf2f(fr[b * Sq + i0 + mf * 16 + lb * 4 + r]);

  const floatx4 z4 = {0.f, 0.f, 0.f, 0.f};
  floatx4 o[4][4];
  float mrun[4][4], lrun[4][4];
#pragma unroll
  for (int mf = 0; mf < 4; ++mf)
#pragma unroll
    for (int x = 0; x < 4; ++x) {
      o[mf][x] = z4;
      mrun[mf][x] = -1e30f;
      lrun[mf][x] = 0.0f;
    }

  for (int jt = 0; jt <= wq; ++jt) {
    const int j0 = jt * 64;
    floatx4 s[4][4];
#pragma unroll
    for (int mf = 0; mf < 4; ++mf)
#pragma unroll
      for (int jf = 0; jf < 4; ++jf) s[mf][jf] = z4;

#pragma unroll
    for (int tt = 0; tt < 2; ++tt) {
      short8 kf[4];
#pragma unroll
      for (int jf = 0; jf < 4; ++jf)
        kf[jf] = *(const short8*)&kq[kbase + (long)(j0 + jf * 16 + la) * Dq + tt * 32 + lb * 8];
#pragma unroll
      for (int mf = 0; mf < 4; ++mf)
#pragma unroll
        for (int jf = 0; jf < 4; ++jf)
          s[mf][jf] = __builtin_amdgcn_mfma_f32_16x16x32_bf16(qf[mf][tt], kf[jf], s[mf][jf], 0, 0, 0);
    }

    const bool diag = (jt == wq);
#pragma unroll
    for (int mf = 0; mf < 4; ++mf)
#pragma unroll
      for (int jf = 0; jf < 4; ++jf)
#pragma unroll
        for (int r = 0; r < 4; ++r) {
          float x = s[mf][jf][r] * frs[mf][r];
          if (diag && (j0 + jf * 16 + la) >= (i0 + mf * 16 + lb * 4 + r)) x = -1e30f;
          s[mf][jf][r] = x;
        }

#pragma unroll
    for (int mf = 0; mf < 4; ++mf)
#pragma unroll
      for (int r = 0; r < 4; ++r) {
        float pm = fmaxf(fmaxf(s[mf][0][r], s[mf][1][r]), fmaxf(s[mf][2][r], s[mf][3][r]));
        pm = fmaxf(pm, __shfl_xor(pm, 1));
        pm = fmaxf(pm, __shfl_xor(pm, 2));
        pm = fmaxf(pm, __shfl_xor(pm, 4));
        pm = fmaxf(pm, __shfl_xor(pm, 8));
        const float mo = mrun[mf][r];
        const float mn = fmaxf(mo, pm);
        const float sc = __expf(mo - mn);
        mrun[mf][r] = mn;
        float rs = 0.0f;
#pragma unroll
        for (int jf = 0; jf < 4; ++jf) {
          const float p = __expf(s[mf][jf][r] - mn);
          s[mf][jf][r] = p;
          rs += p;
        }
        rs += __shfl_xor(rs, 1);
        rs += __shfl_xor(rs, 2);
        rs += __shfl_xor(rs, 4);
        rs += __shfl_xor(rs, 8);
        lrun[mf][r] = lrun[mf][r] * sc + rs;
#pragma unroll
        for (int df = 0; df < 4; ++df) o[mf][df][r] *= sc;
      }

    // P tile is wave-private LDS; same-wave ds_write->ds_read, no barrier
#pragma unroll
    for (int mf = 0; mf < 4; ++mf)
#pragma unroll
      for (int jf = 0; jf < 4; ++jf)
#pragma unroll
        for (int r = 0; r < 4; ++r)
          P[w4][(mf * 16 + lb * 4 + r) * 72 + jf * 16 + la] = f2bf(s[mf][jf][r]);

#pragma unroll
    for (int tt = 0; tt < 2; ++tt) {
      short8 pf[4], vf[4];
#pragma unroll
      for (int mf = 0; mf < 4; ++mf)
        pf[mf] = *(const short8*)&P[w4][(mf * 16 + la) * 72 + tt * 32 + lb * 8];
#pragma unroll
      for (int df = 0; df < 4; ++df)
        vf[df] = *(const short8*)&vt[vbase + (long)(df * 16 + la) * Sq + j0 + tt * 32 + lb * 8];
#pragma unroll
      for (int mf = 0; mf < 4; ++mf)
#pragma unroll
        for (int df = 0; df < 4; ++df)
          o[mf][df] = __builtin_amdgcn_mfma_f32_16x16x32_bf16(pf[mf], vf[df], o[mf][df], 0, 0, 0);
    }
  }

#pragma unroll
  for (int mf = 0; mf < 4; ++mf)
#pragma unroll
    for (int df = 0; df < 4; ++df)
#pragma unroll
      for (int r = 0; r < 4; ++r) {
        const int ii = i0 + mf * 16 + lb * 4 + r;
        const float vv = (ii == 0) ? 0.0f : o[mf][df][r] / lrun[mf][r];
        ao[((long)b * Sq + ii) * Dq + h * 64 + df * 16 + la] = f2bf(vv);
      }
}

// ---------------------------------------------------------------------------
// Fused residual-add + LayerNorm. final_==1: write d_out per flags[0] dtype.
// ---------------------------------------------------------------------------
__global__ __launch_bounds__(256) void ln_kernel(
    float* __restrict__ xf, const ushort_t* __restrict__ add,
    const ushort_t* __restrict__ g, const ushort_t* __restrict__ bb,
    ushort_t* __restrict__ outb, float* __restrict__ outf,
    const int* __restrict__ flags, int final_)
{
  __shared__ float red[2][4];
  const long row = blockIdx.x;
  const int t = threadIdx.x;
  const int c = t * 4;
  float* xr = xf + row * Dq;
  const ushort_t* ar = add + row * Dq;

  floatx4 xv = *(floatx4*)&xr[c];
  ushortx4 av = *(const ushortx4*)&ar[c];
  float v[4];
  float s1 = 0.f, s2 = 0.f;
#pragma unroll
  for (int e = 0; e < 4; ++e) {
    v[e] = xv[e] + bf2f(av[e]);
    s1 += v[e];
    s2 += v[e] * v[e];
  }
#pragma unroll
  for (int m = 1; m < 64; m <<= 1) {
    s1 += __shfl_xor(s1, m);
    s2 += __shfl_xor(s2, m);
  }
  const int lane = t & 63, w = t >> 6;
  if (lane == 0) { red[0][w] = s1; red[1][w] = s2; }
  __syncthreads();
  s1 = red[0][0] + red[0][1] + red[0][2] + red[0][3];
  s2 = red[1][0] + red[1][1] + red[1][2] + red[1][3];
  const float mean = s1 * (1.0f / Dq);
  const float var = fmaxf(s2 * (1.0f / Dq) - mean * mean, 0.0f);
  const float rstd = rsqrtf(var + 1e-5f);
  ushortx4 gv = *(const ushortx4*)&g[c];
  ushortx4 bv = *(const ushortx4*)&bb[c];
  ushortx4 ob;
  floatx4 xo;
#pragma unroll
  for (int e = 0; e < 4; ++e) {
    const float y = (v[e] - mean) * rstd * bf2f(gv[e]) + bf2f(bv[e]);
    xo[e] = y;
    ob[e] = f2bf(y);
  }
  *(floatx4*)&xr[c] = xo;
  if (final_ && !flags[0]) {
    *(floatx4*)&outf[row * Dq + c] = xo;
  } else {
    *(ushortx4*)&outb[row * Dq + c] = ob;
  }
}

// x = qe + pe (fp32 + bf16), y = qa + pe (bf16); flag-aware source dtype
__global__ __launch_bounds__(256) void addpe_kernel(
    const void* __restrict__ qe, const void* __restrict__ qa,
    const void* __restrict__ pe, float* __restrict__ xf,
    ushort_t* __restrict__ xb, ushort_t* __restrict__ yb,
    const int* __restrict__ flags)
{
  const long i = ((long)blockIdx.x * 256 + threadIdx.x) * 8;
  const long sd = i & ((long)Sq * Dq - 1);
  const bool isb = flags[0] != 0;
  float q[8], a[8], p[8];
  if (isb) {
    ushortx8 q8 = *(const ushortx8*)((const ushort_t*)qe + i);
    ushortx8 a8 = *(const ushortx8*)((const ushort_t*)qa + i);
    ushortx8 p8 = *(const ushortx8*)((const ushort_t*)pe + sd);
#pragma unroll
    for (int e = 0; e < 8; ++e) { q[e] = bf2f(q8[e]); a[e] = bf2f(a8[e]); p[e] = bf2f(p8[e]); }
  } else {
    const float* qp = (const float*)qe + i;
    const float* ap = (const float*)qa + i;
    const float* pp = (const float*)pe + sd;
    floatx4 q0 = *(const floatx4*)qp, q1 = *(const floatx4*)(qp + 4);
    floatx4 a0 = *(const floatx4*)ap, a1 = *(const floatx4*)(ap + 4);
    floatx4 p0 = *(const floatx4*)pp, p1 = *(const floatx4*)(pp + 4);
#pragma unroll
    for (int e = 0; e < 4; ++e) {
      q[e] = q0[e]; q[e + 4] = q1[e];
      a[e] = a0[e]; a[e + 4] = a1[e];
      p[e] = p0[e]; p[e + 4] = p1[e];
    }
  }
  ushortx8 xo, yo;
  floatx4 f0, f1;
#pragma unroll
  for (int e = 0; e < 8; ++e) {
    const float xvv = (isb ? q[e] : bf2f(f2bf(q[e]))) + (isb ? p[e] : bf2f(f2bf(p[e])));
    const float yvv = (isb ? a[e] : bf2f(f2bf(a[e]))) + (isb ? p[e] : bf2f(f2bf(p[e])));
    if (e < 4) { f0[e] = xvv; } else { f1[e - 4] = xvv; }
    xo[e] = f2bf(xvv);
    yo[e] = f2bf(yvv);
  }
  *(floatx4*)&xf[i] = f0;
  *(floatx4*)&xf[i + 4] = f1;
  *(ushortx8*)&xb[i] = xo;
  *(ushortx8*)&yb[i] = yo;
}

// dst[z][n][k] = src[z][k][n]; flag-aware source dtype (weights: flags[1])
__global__ __launch_bounds__(256) void transpose_kernel(
    const void* __restrict__ src, ushort_t* __restrict__ dst, int K, int N,
    const int* __restrict__ flags)
{
  __shared__ __align__(16) ushort_t tile[64][72];
  const bool isb = flags[1] != 0;
  const long base = (long)blockIdx.z * K * N;
  const int k0 = blockIdx.y * 64, n0 = blockIdx.x * 64;
  const int t = threadIdx.x;
  const int r = t >> 3;
  const int cc = (t & 7) << 3;
#pragma unroll
  for (int it = 0; it < 2; ++it) {
    const int rr = r + it * 32;
    const long gi = base + (long)(k0 + rr) * N + n0 + cc;
    if (isb) {
      *(short8*)&tile[rr][cc] = *(const short8*)((const ushort_t*)src + gi);
    } else {
      const float* sf = (const float*)src + gi;
      floatx4 v0 = *(const floatx4*)sf;
      floatx4 v1 = *(const floatx4*)(sf + 4);
#pragma unroll
      for (int e = 0; e < 4; ++e) {
        tile[rr][cc + e] = f2bf(v0[e]);
        tile[rr][cc + 4 + e] = f2bf(v1[e]);
      }
    }
  }
  __syncthreads();
#pragma unroll
  for (int it = 0; it < 2; ++it) {
    const int rr = r + it * 32;
    short8 v;
#pragma unroll
    for (int e = 0; e < 8; ++e) v[e] = (short)tile[cc + e][rr];
    *(short8*)&dst[base + (long)(n0 + rr) * K + k0 + cc] = v;
  }
}

// vt[b][h][d][j] = vb[b][j][h*64+d]  (vb is bf16 workspace, no flag needed)
__global__ __launch_bounds__(256) void vtrans_kernel(
    const ushort_t* __restrict__ vb, ushort_t* __restrict__ vt)
{
  __shared__ __align__(16) ushort_t tile[64][72];
  const int b = blockIdx.y >> 4, h = blockIdx.y & 15;
  const int j0 = blockIdx.x * 64;
  const int t = threadIdx.x;
  const int r = t >> 3;
  const int cc = (t & 7) << 3;
#pragma unroll
  for (int it = 0; it < 2; ++it) {
    const int rr = r + it * 32;
    *(short8*)&tile[rr][cc] = *(const short8*)&vb[((long)b * Sq + j0 + rr) * Dq + h * 64 + cc];
  }
  __syncthreads();
#pragma unroll
  for (int it = 0; it < 2; ++it) {
    const int rr = r + it * 32;
    short8 v;
#pragma unroll
    for (int e = 0; e < 8; ++e) v[e] = (short)tile[cc + e][rr];
    *(short8*)&vt[((long)(b * Hq + h) * 64 + rr) * Sq + j0 + cc] = v;
  }
}

extern "C" void kernel_launch(void* const* d_in, const int* in_sizes, int n_in,
                              void* d_out, int out_size, void* d_ws, size_t ws_size,
                              hipStream_t stream)
{
  if (n_in < 18) return;
  const void* qe  = d_in[0];
  const void* qa  = d_in[1];
  const void* fr  = d_in[2];
  const void* pe  = d_in[3];
  const void* Wk  = d_in[4];
  const void* bk  = d_in[5];
  const void* Wv  = d_in[6];
  const void* bv  = d_in[7];
  const void* Wo  = d_in[8];
  const void* bo  = d_in[9];
  const void* W1  = d_in[10];
  const void* b1  = d_in[11];
  const void* W2  = d_in[12];
  const void* b2  = d_in[13];
  const void* g1  = d_in[14];
  const void* be1 = d_in[15];
  const void* g2  = d_in[16];
  const void* be2 = d_in[17];

  char* ws = (char*)d_ws;
  const size_t SM = 243269632L;
  const size_t NEED = SM + 114752L;
  if (ws_size < NEED) return;

  float*    xf   = (float*)   (ws + 0L);
  ushort_t* xb   = (ushort_t*)(ws + 33554432L);
  ushort_t* yb   = (ushort_t*)(ws + 50331648L);
  ushort_t* tmpD = (ushort_t*)(ws + 67108864L);
  ushort_t* WkT  = (ushort_t*)(ws + 83886080L);
  ushort_t* WvT  = (ushort_t*)(ws + 92274688L);
  ushort_t* WoT  = (ushort_t*)(ws + 100663296L);
  ushort_t* W1T  = (ushort_t*)(ws + 109051904L);
  ushort_t* W2T  = (ushort_t*)(ws + 142606336L);
  ushort_t* kb   = (ushort_t*)(ws + 176160768L);
  ushort_t* vbf  = (ushort_t*)(ws + 192937984L);
  ushort_t* vtb  = (ushort_t*)(ws + 209715200L);
  ushort_t* ff1  = kb;  // 64 MiB region, disjoint lifetime

  int*      flags = (int*)(ws + SM);
  ushort_t* frc  = (ushort_t*)(ws + SM + 64);
  ushort_t* bkc  = (ushort_t*)(ws + SM + 16448);
  ushort_t* bvc  = (ushort_t*)(ws + SM + 24640);
  ushort_t* boc  = (ushort_t*)(ws + SM + 32832);
  ushort_t* b1c  = (ushort_t*)(ws + SM + 41024);
  ushort_t* b2c  = (ushort_t*)(ws + SM + 73792);
  ushort_t* g1c  = (ushort_t*)(ws + SM + 81984);
  ushort_t* be1c = (ushort_t*)(ws + SM + 90176);
  ushort_t* g2c  = (ushort_t*)(ws + SM + 98368);
  ushort_t* be2c = (ushort_t*)(ws + SM + 106560);

  probe_kernel<<<1, 64, 0, stream>>>((const ushort_t*)pe, (const ushort_t*)g1, flags);

  {
    CvtArgs a;
    const void* srcs[10] = {fr, bk, bv, bo, b1, b2, g1, be1, g2, be2};
    ushort_t*   dsts[10] = {frc, bkc, bvc, boc, b1c, b2c, g1c, be1c, g2c, be2c};
    const int   ns[10]   = {8192, 4096, 4096, 4096, 16384, 4096, 4096, 4096, 4096, 4096};
    int cum = 0;
    for (int s = 0; s < 10; ++s) {
      a.src[s] = srcs[s]; a.dst[s] = dsts[s]; a.n[s] = ns[s];
      a.fi[s] = (s == 0) ? 0 : 1;
      a.cum[s] = cum;
      cum += (ns[s] + 255) / 256;
    }
    a.cum[10] = cum;
    convert_all_kernel<<<cum, 256, 0, stream>>>(a, flags);
  }

  transpose_kernel<<<dim3(16, 16, 4), 256, 0, stream>>>(Wk, WkT, 1024, 1024, flags);
  transpose_kernel<<<dim3(16, 16, 4), 256, 0, stream>>>(Wv, WvT, 1024, 1024, flags);
  transpose_kernel<<<dim3(16, 16, 4), 256, 0, stream>>>(Wo, WoT, 1024, 1024, flags);
  transpose_kernel<<<dim3(64, 16, 4), 256, 0, stream>>>(W1, W1T, 1024, 4096, flags);
  transpose_kernel<<<dim3(16, 64, 4), 256, 0, stream>>>(W2, W2T, 4096, 1024, flags);

  addpe_kernel<<<4096, 256, 0, stream>>>(qe, qa, pe, xf, xb, yb, flags);

  for (int l = 0; l < 4; ++l) {
    // K-proj (z=0) and V-proj (z=1) batched: 2048 blocks
    gemm_bt_kernel<<<dim3(16, 64, 2), 256, 0, stream>>>(
        xb, WkT + (long)l * 1048576, bkc + l * 1024, kb,
        yb, WvT + (long)l * 1048576, bvc + l * 1024, vbf,
        1024, 1024, 0);
    vtrans_kernel<<<dim3(8, 256), 256, 0, stream>>>(vbf, vtb);
    attn_kernel<<<dim3(256, 2), 256, 0, stream>>>(kb, vtb, frc, vbf);  // ao aliases vbf
    gemm_bt_kernel<<<dim3(16, 64, 1), 256, 0, stream>>>(
        vbf, WoT + (long)l * 1048576, boc + l * 1024, tmpD,
        vbf, WoT + (long)l * 1048576, boc + l * 1024, tmpD,
        1024, 1024, 0);
    ln_kernel<<<8192, 256, 0, stream>>>(xf, tmpD, g1c + l * 1024, be1c + l * 1024, xb, nullptr, flags, 0);
    gemm_bt_kernel<<<dim3(64, 64, 1), 256, 0, stream>>>(
        xb, W1T + (long)l * 4194304, b1c + l * 4096, ff1,
        xb, W1T + (long)l * 4194304, b1c + l * 4096, ff1,
        4096, 1024, 1);
    gemm_bt_kernel<<<dim3(16, 64, 1), 256, 0, stream>>>(
        ff1, W2T + (long)l * 4194304, b2c + l * 1024, tmpD,
        ff1, W2T + (long)l * 4194304, b2c + l * 1024, tmpD,
        1024, 4096, 0);
    if (l == 3) {
      ln_kernel<<<8192, 256, 0, stream>>>(xf, tmpD, g2c + l * 1024, be2c + l * 1024,
                                          (ushort_t*)d_out, (float*)d_out, flags, 1);
    } else {
      ln_kernel<<<8192, 256, 0, stream>>>(xf, tmpD, g2c + l * 1024, be2c + l * 1024,
                                          xb, nullptr, flags, 0);
    }
  }
}